// Round 2
// baseline (359.086 us; speedup 1.0000x reference)
//
#include <hip/hip_runtime.h>
#include <stdint.h>

#define TOKENS 65536
#define CDIM 384
#define NEXP 5
#define LDA 40   // padded LDS row stride in shorts (80 B = 5 granules of 16 B -> conflict-free b128)

typedef __attribute__((ext_vector_type(8))) short short8;
typedef __attribute__((ext_vector_type(4))) float floatx4;

__device__ inline unsigned short f2bf(float f) {
    union { float f; uint32_t u; } v; v.f = f;
    uint32_t r = v.u + 0x7fffu + ((v.u >> 16) & 1u);   // RNE for normal values
    return (unsigned short)(r >> 16);
}

// ---------------- Kernel 1: router, 2 threads/token, sequential fp64 ----------------
// fp64 ranking proven against np ref in R1 (absmax 7.8e-3, no top-k flips).
__global__ __launch_bounds__(256) void router_kernel(const float* __restrict__ x,
                                                     const float* __restrict__ Wg,
                                                     float* __restrict__ G) {
    int T = blockIdx.x * 256 + threadIdx.x;          // 131072 threads
    int tok = T >> 1, half = T & 1;
    const float4* xr = (const float4*)(x + (size_t)tok * CDIM) + half * 48;
    int cbase = half * 192;
    double p[NEXP] = {0.0, 0.0, 0.0, 0.0, 0.0};
    #pragma unroll 8
    for (int j = 0; j < 48; ++j) {
        float4 v = xr[j];                            // per-lane row stream, L1-line reuse
        int c = cbase + j * 4;                       // uniform -> Wg reads scalarize
        #pragma unroll
        for (int e = 0; e < NEXP; ++e) {
            p[e] += (double)v.x * (double)Wg[(c + 0) * NEXP + e]
                  + (double)v.y * (double)Wg[(c + 1) * NEXP + e]
                  + (double)v.z * (double)Wg[(c + 2) * NEXP + e]
                  + (double)v.w * (double)Wg[(c + 3) * NEXP + e];
        }
    }
    #pragma unroll
    for (int e = 0; e < NEXP; ++e) p[e] += __shfl_xor(p[e], 1, 64);
    if (half == 0) {
        int i0 = 0;                                  // strict > : ties -> lowest index (lax.top_k)
        #pragma unroll
        for (int e = 1; e < NEXP; ++e) if (p[e] > p[i0]) i0 = e;
        int i1 = (i0 == 0) ? 1 : 0;
        #pragma unroll
        for (int e = 0; e < NEXP; ++e) if (e != i0 && p[e] > p[i1]) i1 = e;
        float d  = (float)(p[i1] - p[i0]);           // <= 0
        float e1 = expf(d);
        float s  = 1.0f + e1;
        float* gr = G + (size_t)tok * NEXP;
        #pragma unroll
        for (int e = 0; e < NEXP; ++e) gr[e] = 0.0f;
        gr[i0] = 1.0f / s;
        gr[i1] = e1 / s;
    }
}

// ---------------- Kernel 2: We[e][c][d] fp32 -> WeT[e][d][c] bf16 (tiled transpose) --
__global__ __launch_bounds__(256) void convert_we(const float* __restrict__ We,
                                                  unsigned short* __restrict__ WeT) {
    __shared__ float tile[64][65];
    int e  = blockIdx.z;
    int c0 = blockIdx.x * 64, d0 = blockIdx.y * 64;
    int t  = threadIdx.x;
    const float* src = We + (size_t)e * CDIM * CDIM;
    int dr = t & 15, cr = t >> 4;
    for (int s = 0; s < 64; s += 16) {
        float4 v = *(const float4*)&src[(size_t)(c0 + cr + s) * CDIM + d0 + dr * 4];
        tile[cr + s][dr * 4 + 0] = v.x;
        tile[cr + s][dr * 4 + 1] = v.y;
        tile[cr + s][dr * 4 + 2] = v.z;
        tile[cr + s][dr * 4 + 3] = v.w;
    }
    __syncthreads();
    unsigned short* dst = WeT + (size_t)e * CDIM * CDIM;
    int c4 = t & 15, drow = t >> 4;
    for (int s = 0; s < 64; s += 16) {
        int d = drow + s;
        ushort4 o;
        o.x = f2bf(tile[c4 * 4 + 0][d]);
        o.y = f2bf(tile[c4 * 4 + 1][d]);
        o.z = f2bf(tile[c4 * 4 + 2][d]);
        o.w = f2bf(tile[c4 * 4 + 3][d]);
        *(ushort4*)&dst[(size_t)(d0 + d) * CDIM + c0 + c4 * 4] = o;
    }
}

// ---------------- Kernel 3: fused dense MoE GEMM + combine + bias + LeakyReLU -------
__global__ __launch_bounds__(512, 2) void moe_kernel(const float* __restrict__ x,
                                                     const unsigned short* __restrict__ WeT,
                                                     const float* __restrict__ G,
                                                     const float* __restrict__ be,
                                                     float* __restrict__ out) {
    const int BM = 128, BK = 32;
    int bid = blockIdx.x;
    int nt = bid % 3, mt = bid / 3;
    int m0 = mt * BM, n0 = nt * 128;
    int t = threadIdx.x;
    int lane = t & 63, wid = t >> 6;
    int wm = wid & 1, wn = wid >> 1;                 // wave tile 64(m) x 32(n)
    __shared__ __align__(16) unsigned short As[BM * LDA];          // 10 KB
    __shared__ __align__(16) unsigned short Bs[NEXP][128 * LDA];   // 50 KB

    floatx4 acc[NEXP][4][2];
    #pragma unroll
    for (int e = 0; e < NEXP; ++e)
        #pragma unroll
        for (int i = 0; i < 4; ++i)
            #pragma unroll
            for (int j = 0; j < 2; ++j)
                acc[e][i][j] = (floatx4){0.0f, 0.0f, 0.0f, 0.0f};

    int srow = t >> 2, sp = t & 3;
    const float*          xrow = x   + (size_t)(m0 + srow) * CDIM + sp * 8;
    const unsigned short* brow = WeT + (size_t)(n0 + srow) * CDIM + sp * 8;
    int q = lane >> 4, cc = lane & 15;

    for (int kc = 0; kc < 12; ++kc) {
        int k0 = kc * BK;
        __syncthreads();
        float4 a0 = *(const float4*)(xrow + k0);
        float4 a1 = *(const float4*)(xrow + k0 + 4);
        short8 av;
        av[0] = f2bf(a0.x); av[1] = f2bf(a0.y); av[2] = f2bf(a0.z); av[3] = f2bf(a0.w);
        av[4] = f2bf(a1.x); av[5] = f2bf(a1.y); av[6] = f2bf(a1.z); av[7] = f2bf(a1.w);
        *(short8*)&As[srow * LDA + sp * 8] = av;
        #pragma unroll
        for (int e = 0; e < NEXP; ++e)
            *(short8*)&Bs[e][srow * LDA + sp * 8] =
                *(const short8*)(brow + (size_t)e * CDIM * CDIM + k0);
        __syncthreads();

        short8 af[4];
        #pragma unroll
        for (int i = 0; i < 4; ++i)
            af[i] = *(const short8*)&As[(wm * 64 + i * 16 + cc) * LDA + q * 8];
        #pragma unroll
        for (int e = 0; e < NEXP; ++e) {
            short8 b0 = *(const short8*)&Bs[e][(wn * 32 + cc) * LDA + q * 8];
            short8 b1 = *(const short8*)&Bs[e][(wn * 32 + 16 + cc) * LDA + q * 8];
            #pragma unroll
            for (int i = 0; i < 4; ++i) {
                acc[e][i][0] = __builtin_amdgcn_mfma_f32_16x16x32_bf16(af[i], b0, acc[e][i][0], 0, 0, 0);
                acc[e][i][1] = __builtin_amdgcn_mfma_f32_16x16x32_bf16(af[i], b1, acc[e][i][1], 0, 0, 0);
            }
        }
    }

    // epilogue: y = leaky( sum_e g_e * (acc_e + be_e) )   [C/D: col=lane&15, row=q*4+r]
    float bes[2][NEXP];
    #pragma unroll
    for (int j = 0; j < 2; ++j) {
        int oc = n0 + wn * 32 + j * 16 + cc;
        #pragma unroll
        for (int e = 0; e < NEXP; ++e) bes[j][e] = be[e * CDIM + oc];
    }
    #pragma unroll
    for (int i = 0; i < 4; ++i) {
        #pragma unroll
        for (int r = 0; r < 4; ++r) {
            int tok = m0 + wm * 64 + i * 16 + q * 4 + r;
            const float* g = G + (size_t)tok * NEXP;
            float g0 = g[0], g1 = g[1], g2 = g[2], g3 = g[3], g4 = g[4];
            #pragma unroll
            for (int j = 0; j < 2; ++j) {
                int oc = n0 + wn * 32 + j * 16 + cc;
                float v = g0 * (acc[0][i][j][r] + bes[j][0])
                        + g1 * (acc[1][i][j][r] + bes[j][1])
                        + g2 * (acc[2][i][j][r] + bes[j][2])
                        + g3 * (acc[3][i][j][r] + bes[j][3])
                        + g4 * (acc[4][i][j][r] + bes[j][4]);
                v = v > 0.0f ? v : 0.01f * v;
                out[(size_t)tok * CDIM + oc] = v;
            }
        }
    }
}

extern "C" void kernel_launch(void* const* d_in, const int* in_sizes, int n_in,
                              void* d_out, int out_size, void* d_ws, size_t ws_size,
                              hipStream_t stream) {
    const float* x  = (const float*)d_in[0];
    const float* Wg = (const float*)d_in[1];
    const float* We = (const float*)d_in[2];
    const float* be = (const float*)d_in[3];
    float* out = (float*)d_out;

    float* G = (float*)d_ws;                                                    // 1.31 MB
    unsigned short* WeT =
        (unsigned short*)((char*)d_ws + (size_t)TOKENS * NEXP * sizeof(float)); // 1.47 MB

    router_kernel<<<512, 256, 0, stream>>>(x, Wg, G);
    convert_we<<<dim3(6, 6, 5), 256, 0, stream>>>(We, WeT);
    moe_kernel<<<1536, 512, 0, stream>>>(x, WeT, G, be, out);
}

// Round 3
// 353.933 us; speedup vs baseline: 1.0146x; 1.0146x over previous
//
#include <hip/hip_runtime.h>
#include <stdint.h>

#define TOKENS 65536
#define CDIM 384
#define NEXP 5
#define WE_STRIDE (CDIM * CDIM)

typedef __attribute__((ext_vector_type(8))) short short8;
typedef __attribute__((ext_vector_type(4))) float floatx4;

__device__ inline unsigned short f2bf(float f) {
    union { float f; uint32_t u; } v; v.f = f;
    uint32_t r = v.u + 0x7fffu + ((v.u >> 16) & 1u);   // RNE for normal values
    return (unsigned short)(r >> 16);
}

__device__ inline void load_lds16(const void* g, void* l) {
    // async global->LDS, 16B per lane; dest = wave-uniform base + lane*16
    __builtin_amdgcn_global_load_lds((const __attribute__((address_space(1))) void*)g,
                                     (__attribute__((address_space(3))) void*)l, 16, 0, 0);
}

// ---------------- Kernel 1: router v3 — token-per-thread, LDS-staged x ---------------
// Coalesced x loads; Wg index is wave-uniform -> scalar loads; fp64 accumulate
// (ranking-safe, proven R1/R2); per-thread top-2 so NO shuffle reduction at all.
__global__ __launch_bounds__(256) void router_kernel(const float* __restrict__ x,
                                                     const float* __restrict__ Wg,
                                                     float* __restrict__ G) {
    __shared__ __align__(16) float xs[256][36];          // stride 36 fl = 9 granules: conflict-free b128
    int t = threadIdx.x;
    int tok0 = blockIdx.x * 256;
    double p0 = 0, p1 = 0, p2 = 0, p3 = 0, p4 = 0;
    int lrow = t >> 3, c4 = t & 7;
    const float* xbase = x + (size_t)tok0 * CDIM;
    for (int kc = 0; kc < 12; ++kc) {
        int k0 = kc * 32;
        __syncthreads();
        #pragma unroll
        for (int i = 0; i < 8; ++i) {                    // 256x32 fp32 tile, fully coalesced
            int row = lrow + 32 * i;
            *(float4*)&xs[row][c4 * 4] = *(const float4*)&xbase[(size_t)row * CDIM + k0 + c4 * 4];
        }
        __syncthreads();
        #pragma unroll
        for (int jj = 0; jj < 8; ++jj) {
            float4 v = *(const float4*)&xs[t][jj * 4];   // own row: stride-9 granules, conflict-free
            const float* wr = Wg + (k0 + jj * 4) * NEXP; // wave-uniform -> s_load
            p0 += (double)v.x * (double)wr[0] + (double)v.y * (double)wr[5]
                + (double)v.z * (double)wr[10] + (double)v.w * (double)wr[15];
            p1 += (double)v.x * (double)wr[1] + (double)v.y * (double)wr[6]
                + (double)v.z * (double)wr[11] + (double)v.w * (double)wr[16];
            p2 += (double)v.x * (double)wr[2] + (double)v.y * (double)wr[7]
                + (double)v.z * (double)wr[12] + (double)v.w * (double)wr[17];
            p3 += (double)v.x * (double)wr[3] + (double)v.y * (double)wr[8]
                + (double)v.z * (double)wr[13] + (double)v.w * (double)wr[18];
            p4 += (double)v.x * (double)wr[4] + (double)v.y * (double)wr[9]
                + (double)v.z * (double)wr[14] + (double)v.w * (double)wr[19];
        }
    }
    double pa[NEXP] = {p0, p1, p2, p3, p4};
    int i0 = 0; double m0v = pa[0];
    #pragma unroll
    for (int e = 1; e < NEXP; ++e) if (pa[e] > m0v) { m0v = pa[e]; i0 = e; }   // strict >: lax.top_k ties
    int i1 = -1; double m1v = -1e300;
    #pragma unroll
    for (int e = 0; e < NEXP; ++e) if (e != i0 && pa[e] > m1v) { m1v = pa[e]; i1 = e; }
    float d  = (float)(m1v - m0v);                       // <= 0
    float e1 = expf(d);
    float inv = 1.0f / (1.0f + e1);
    float ga = inv, gb = e1 * inv;
    float* gr = G + (size_t)(tok0 + t) * NEXP;
    #pragma unroll
    for (int e = 0; e < NEXP; ++e)
        gr[e] = (e == i0) ? ga : ((e == i1) ? gb : 0.0f);
}

// ---------------- Kernel 2: We[e][c][d] fp32 -> WeT[e][d][c] bf16 (tiled transpose) --
__global__ __launch_bounds__(256) void convert_we(const float* __restrict__ We,
                                                  unsigned short* __restrict__ WeT) {
    __shared__ float tile[64][65];
    int e  = blockIdx.z;
    int c0 = blockIdx.x * 64, d0 = blockIdx.y * 64;
    int t  = threadIdx.x;
    const float* src = We + (size_t)e * WE_STRIDE;
    int dr = t & 15, cr = t >> 4;
    for (int s = 0; s < 64; s += 16) {
        float4 v = *(const float4*)&src[(size_t)(c0 + cr + s) * CDIM + d0 + dr * 4];
        tile[cr + s][dr * 4 + 0] = v.x;
        tile[cr + s][dr * 4 + 1] = v.y;
        tile[cr + s][dr * 4 + 2] = v.z;
        tile[cr + s][dr * 4 + 3] = v.w;
    }
    __syncthreads();
    unsigned short* dst = WeT + (size_t)e * WE_STRIDE;
    int c4 = t & 15, drow = t >> 4;
    for (int s = 0; s < 64; s += 16) {
        int d = drow + s;
        ushort4 o;
        o.x = f2bf(tile[c4 * 4 + 0][d]);
        o.y = f2bf(tile[c4 * 4 + 1][d]);
        o.z = f2bf(tile[c4 * 4 + 2][d]);
        o.w = f2bf(tile[c4 * 4 + 3][d]);
        *(ushort4*)&dst[(size_t)(d0 + d) * CDIM + c0 + c4 * 4] = o;
    }
}

// ---------------- Kernel 3: fused dense MoE GEMM + combine + bias + LeakyReLU -------
// tile 128m x 64n, 8 waves (wave-tile 64x16): acc = 5x4 floatx4 = 80 regs ->
// launch_bounds(512,4) caps unified regs at 128 => 2 blocks/CU (vs 1 before).
// LDS 28 KB: As granules 0..511, Bs 512..1791; granule swizzle (g + (row>>1))&3
// keeps async-DMA dest linear AND spreads frag reads across granule-quads.
__global__ __launch_bounds__(512, 4) void moe_kernel(const float* __restrict__ x,
                                                     const unsigned short* __restrict__ WeT,
                                                     const float* __restrict__ G,
                                                     const float* __restrict__ be,
                                                     float* __restrict__ out) {
    const int BM = 128, BN = 64, BK = 32;
    int bid = blockIdx.x;
    int nt = bid % 6, mt = bid / 6;                      // consecutive bids share m-tile (L3 x reuse)
    int m0 = mt * BM, n0 = nt * BN;
    int t = threadIdx.x, lane = t & 63, wid = t >> 6;
    int wm = wid & 1, wn = wid >> 1;                     // 2(m) x 4(n) waves
    int q = lane >> 4, cc = lane & 15;

    __shared__ __align__(16) unsigned short S[14336];    // 28 KB

    floatx4 acc[NEXP][4];
    #pragma unroll
    for (int e = 0; e < NEXP; ++e)
        #pragma unroll
        for (int i = 0; i < 4; ++i)
            acc[e][i] = (floatx4){0.0f, 0.0f, 0.0f, 0.0f};

    // ---- A staging (VGPR path: fp32 -> bf16 conversion needed) ----
    int srow = t >> 2, sp = t & 3;
    const float* xrow = x + (size_t)(m0 + srow) * CDIM + sp * 8;
    unsigned short* aw = S + (size_t)(4 * srow + ((sp + (srow >> 1)) & 3)) * 8;

    // ---- B staging via async global_load_lds (3 reps cover 5*64 rows * 4 granules) ----
    const unsigned short* bsrc[3];
    unsigned short* bdst[3];
    #pragma unroll
    for (int rep = 0; rep < 3; ++rep) {
        int idx = rep * 512 + t;                         // flat phys granule in Bs (valid < 1280)
        int e = idx >> 8, pe = idx & 255, r = pe >> 2, gp = pe & 3;
        int gl = (gp - (r >> 1)) & 3;                    // logical k-granule stored at phys gp
        bsrc[rep] = WeT + (size_t)e * WE_STRIDE + (size_t)(n0 + r) * CDIM + gl * 8;
        bdst[rep] = S + (size_t)(512 + rep * 512 + wid * 64) * 8;   // wave-uniform base
    }

    // ---- fragment read offsets (loop-invariant; (row>>1)&3 == (cc>>1)&3 for all i/e) ----
    int perm = (q + (cc >> 1)) & 3;
    const unsigned short* abase = S + (size_t)(4 * (wm * 64 + cc) + perm) * 8;
    const unsigned short* bbase = S + (size_t)(512 + 4 * (wn * 16 + cc) + perm) * 8;

    for (int kc = 0; kc < 12; ++kc) {
        int k0 = kc * BK;
        __syncthreads();
        load_lds16(bsrc[0] + k0, bdst[0]);               // start DMA first
        load_lds16(bsrc[1] + k0, bdst[1]);
        if (t < 256) load_lds16(bsrc[2] + k0, bdst[2]);
        float4 a0 = *(const float4*)(xrow + k0);         // overlaps with B in flight
        float4 a1 = *(const float4*)(xrow + k0 + 4);
        short8 av;
        av[0] = f2bf(a0.x); av[1] = f2bf(a0.y); av[2] = f2bf(a0.z); av[3] = f2bf(a0.w);
        av[4] = f2bf(a1.x); av[5] = f2bf(a1.y); av[6] = f2bf(a1.z); av[7] = f2bf(a1.w);
        *(short8*)aw = av;
        __syncthreads();                                 // compiler drains vmcnt+lgkm here

        short8 af[4];
        #pragma unroll
        for (int i = 0; i < 4; ++i)
            af[i] = *(const short8*)(abase + i * 512);   // +64 granules per i (imm offset)
        #pragma unroll
        for (int e = 0; e < NEXP; ++e) {
            short8 b = *(const short8*)(bbase + e * 2048);  // +256 granules per expert
            #pragma unroll
            for (int i = 0; i < 4; ++i)
                acc[e][i] = __builtin_amdgcn_mfma_f32_16x16x32_bf16(af[i], b, acc[e][i], 0, 0, 0);
        }
    }

    // ---- epilogue: stage gates in LDS (reuse As), then combine+bias+leaky ----
    __syncthreads();
    float* Gs = (float*)S;                               // 640 floats = 2.56 KB
    Gs[t] = G[(size_t)m0 * NEXP + t];
    if (t < 128) Gs[512 + t] = G[(size_t)m0 * NEXP + 512 + t];
    float bes[NEXP];
    int oc = n0 + wn * 16 + cc;
    #pragma unroll
    for (int e = 0; e < NEXP; ++e) bes[e] = be[e * CDIM + oc];
    __syncthreads();

    #pragma unroll
    for (int i = 0; i < 4; ++i) {
        #pragma unroll
        for (int r = 0; r < 4; ++r) {
            int trow = wm * 64 + i * 16 + q * 4 + r;     // C/D: col=cc, row=q*4+r
            float g0 = Gs[trow * NEXP + 0], g1 = Gs[trow * NEXP + 1],
                  g2 = Gs[trow * NEXP + 2], g3 = Gs[trow * NEXP + 3],
                  g4 = Gs[trow * NEXP + 4];              // same addr across cc -> broadcast
            float v = g0 * (acc[0][i][r] + bes[0]) + g1 * (acc[1][i][r] + bes[1])
                    + g2 * (acc[2][i][r] + bes[2]) + g3 * (acc[3][i][r] + bes[3])
                    + g4 * (acc[4][i][r] + bes[4]);
            v = v > 0.0f ? v : 0.01f * v;
            out[(size_t)(m0 + trow) * CDIM + oc] = v;
        }
    }
}

extern "C" void kernel_launch(void* const* d_in, const int* in_sizes, int n_in,
                              void* d_out, int out_size, void* d_ws, size_t ws_size,
                              hipStream_t stream) {
    const float* x  = (const float*)d_in[0];
    const float* Wg = (const float*)d_in[1];
    const float* We = (const float*)d_in[2];
    const float* be = (const float*)d_in[3];
    float* out = (float*)d_out;

    float* G = (float*)d_ws;                                                    // 1.31 MB
    unsigned short* WeT =
        (unsigned short*)((char*)d_ws + (size_t)TOKENS * NEXP * sizeof(float)); // 1.47 MB

    router_kernel<<<TOKENS / 256, 256, 0, stream>>>(x, Wg, G);
    convert_we<<<dim3(6, 6, 5), 256, 0, stream>>>(We, WeT);
    moe_kernel<<<(TOKENS / 128) * 6, 512, 0, stream>>>(x, WeT, G, be, out);
}

// Round 4
// 352.335 us; speedup vs baseline: 1.0192x; 1.0045x over previous
//
#include <hip/hip_runtime.h>
#include <stdint.h>

#define TOKENS 65536
#define CDIM 384
#define NEXP 5
#define WE_STRIDE (CDIM * CDIM)

typedef __attribute__((ext_vector_type(8))) short short8;
typedef __attribute__((ext_vector_type(4))) float floatx4;

__device__ inline unsigned short f2bf(float f) {
    union { float f; uint32_t u; } v; v.f = f;
    uint32_t r = v.u + 0x7fffu + ((v.u >> 16) & 1u);   // RNE for normal values
    return (unsigned short)(r >> 16);
}

__device__ inline void load_lds16(const void* g, void* l) {
    // async global->LDS, 16B/lane; dest = wave-uniform base + lane*16 (R3-verified)
    __builtin_amdgcn_global_load_lds((const __attribute__((address_space(1))) void*)g,
                                     (__attribute__((address_space(3))) void*)l, 16, 0, 0);
}

// ---------------- Kernel 1: router v4 — token/thread, LDS x + LDS Wg, pipelined -----
__global__ __launch_bounds__(256) void router_kernel(const float* __restrict__ x,
                                                     const float* __restrict__ Wg,
                                                     float* __restrict__ G) {
    __shared__ __align__(16) float xs[256 * 36];         // row stride 36 fl = 9 granules
    __shared__ __align__(16) float wgs[CDIM * NEXP];     // 7.7 KB
    int t = threadIdx.x;
    int tok0 = blockIdx.x * 256;
    for (int i = t; i < CDIM * NEXP; i += 256) wgs[i] = Wg[i];
    double p0 = 0, p1 = 0, p2 = 0, p3 = 0, p4 = 0;
    int lrow = t >> 3, c4 = (t & 7) * 4;
    const float* xbase = x + (size_t)tok0 * CDIM;
    float4 xr[8];
    #pragma unroll
    for (int i = 0; i < 8; ++i)
        xr[i] = *(const float4*)&xbase[(size_t)(lrow + 32 * i) * CDIM + c4];
    #pragma unroll
    for (int kc = 0; kc < 12; ++kc) {
        int k0 = kc * 32;
        __syncthreads();                                 // xs readers (kc-1) done
        #pragma unroll
        for (int i = 0; i < 8; ++i)
            *(float4*)&xs[(lrow + 32 * i) * 36 + c4] = xr[i];
        __syncthreads();                                 // xs[kc] ready (+ wgs on kc=0)
        if (kc < 11) {                                   // prefetch lands during compute
            #pragma unroll
            for (int i = 0; i < 8; ++i)
                xr[i] = *(const float4*)&xbase[(size_t)(lrow + 32 * i) * CDIM + k0 + 32 + c4];
        }
        #pragma unroll
        for (int jj = 0; jj < 8; ++jj) {
            float4 v = *(const float4*)&xs[t * 36 + jj * 4];
            const float4* wr = (const float4*)&wgs[(k0 + jj * 4) * NEXP];  // 16B-aligned
            float4 w0 = wr[0], w1 = wr[1], w2 = wr[2], w3 = wr[3], w4 = wr[4];
            p0 += (double)v.x * w0.x + (double)v.y * w1.y + (double)v.z * w2.z + (double)v.w * w3.w;
            p1 += (double)v.x * w0.y + (double)v.y * w1.z + (double)v.z * w2.w + (double)v.w * w4.x;
            p2 += (double)v.x * w0.z + (double)v.y * w1.w + (double)v.z * w3.x + (double)v.w * w4.y;
            p3 += (double)v.x * w0.w + (double)v.y * w2.x + (double)v.z * w3.y + (double)v.w * w4.z;
            p4 += (double)v.x * w1.x + (double)v.y * w2.y + (double)v.z * w3.z + (double)v.w * w4.w;
        }
    }
    double pa[NEXP] = {p0, p1, p2, p3, p4};
    int i0 = 0; double m0v = pa[0];
    #pragma unroll
    for (int e = 1; e < NEXP; ++e) if (pa[e] > m0v) { m0v = pa[e]; i0 = e; }  // strict >: lax.top_k ties
    int i1 = -1; double m1v = -1e300;
    #pragma unroll
    for (int e = 0; e < NEXP; ++e) if (e != i0 && pa[e] > m1v) { m1v = pa[e]; i1 = e; }
    float d  = (float)(m1v - m0v);
    float e1 = expf(d);
    float inv = 1.0f / (1.0f + e1);
    float* gr = G + (size_t)(tok0 + t) * NEXP;
    #pragma unroll
    for (int e = 0; e < NEXP; ++e)
        gr[e] = (e == i0) ? inv : ((e == i1) ? e1 * inv : 0.0f);
}

// ---------------- Kernel 2: We[e][c][d] fp32 -> WeT[e][d][c] bf16 (tiled transpose) --
__global__ __launch_bounds__(256) void convert_we(const float* __restrict__ We,
                                                  unsigned short* __restrict__ WeT) {
    __shared__ float tile[64][65];
    int e  = blockIdx.z;
    int c0 = blockIdx.x * 64, d0 = blockIdx.y * 64;
    int t  = threadIdx.x;
    const float* src = We + (size_t)e * WE_STRIDE;
    int dr = t & 15, cr = t >> 4;
    for (int s = 0; s < 64; s += 16) {
        float4 v = *(const float4*)&src[(size_t)(c0 + cr + s) * CDIM + d0 + dr * 4];
        tile[cr + s][dr * 4 + 0] = v.x;
        tile[cr + s][dr * 4 + 1] = v.y;
        tile[cr + s][dr * 4 + 2] = v.z;
        tile[cr + s][dr * 4 + 3] = v.w;
    }
    __syncthreads();
    unsigned short* dst = WeT + (size_t)e * WE_STRIDE;
    int c4 = t & 15, drow = t >> 4;
    for (int s = 0; s < 64; s += 16) {
        int d = drow + s;
        ushort4 o;
        o.x = f2bf(tile[c4 * 4 + 0][d]);
        o.y = f2bf(tile[c4 * 4 + 1][d]);
        o.z = f2bf(tile[c4 * 4 + 2][d]);
        o.w = f2bf(tile[c4 * 4 + 3][d]);
        *(ushort4*)&dst[(size_t)(d0 + d) * CDIM + c0 + c4 * 4] = o;
    }
}

// ---------------- Kernel 3: pipelined dense MoE GEMM + combine + bias + LeakyReLU ---
// 128m x 64n block, 8 waves as 4(m) x 2(n) -> wave tile 32x32 (full 128B line stores).
// A (bf16, VGPR-staged) and B (async DMA) both double-buffered; ONE sync per kc:
//   convert->As[buf]; sync (drains DMA[kc], issued a full compute phase ago);
//   issue DMA[kc+1] + x prefetch; frag reads + MFMA on buf.
// LDS 56 KB, launch_bounds(512,2): 1 block/CU — latency hidden by the pipeline.
__global__ __launch_bounds__(512, 2) void moe_kernel(const float* __restrict__ x,
                                                     const unsigned short* __restrict__ WeT,
                                                     const float* __restrict__ G,
                                                     const float* __restrict__ be,
                                                     float* __restrict__ out) {
    int bid = blockIdx.x;
    int nt = bid % 6, mt = bid / 6;                      // consecutive bids share m-tile
    int m0 = mt * 128, n0 = nt * 64;
    int t = threadIdx.x, lane = t & 63, wid = t >> 6;
    int wm = wid >> 1, wn = wid & 1;                     // 4(m) x 2(n) waves
    int q = lane >> 4, cc = lane & 15;

    // granules (16B units): A dbuf 0..1023, B dbuf 1024..3583  => 57344 B
    __shared__ __align__(16) unsigned short S[3584 * 8];

    floatx4 acc[NEXP][2][2];
    #pragma unroll
    for (int e = 0; e < NEXP; ++e)
        #pragma unroll
        for (int i = 0; i < 2; ++i)
            #pragma unroll
            for (int j = 0; j < 2; ++j)
                acc[e][i][j] = (floatx4){0.0f, 0.0f, 0.0f, 0.0f};

    // A staging: thread -> (row, 16B piece), swizzled dest granule
    int srow = t >> 2, sp = t & 3;
    const float* xrow = x + (size_t)(m0 + srow) * CDIM + sp * 8;
    int agr = 4 * srow + ((sp + (srow >> 1)) & 3);       // + buf*512

    // B staging via DMA: 1280 granules/kc over 2.5 reps (R3-verified mapping)
    const unsigned short* bsrc[3];
    int bdst_gr[3];
    #pragma unroll
    for (int rep = 0; rep < 3; ++rep) {
        int idx = rep * 512 + t;
        int e = idx >> 8, pe = idx & 255, r = pe >> 2, gp = pe & 3;
        int gl = (gp - (r >> 1)) & 3;                    // logical k-granule at phys slot
        bsrc[rep] = WeT + (size_t)e * WE_STRIDE + (size_t)(n0 + r) * CDIM + gl * 8;
        bdst_gr[rep] = 1024 + rep * 512 + wid * 64;      // + buf*1280 (+lane via DMA)
    }

    // fragment read bases (loop-invariant perm: (row>>1)&3 == (cc>>1)&3)
    int perm = (q + (cc >> 1)) & 3;
    int a_gr = 4 * (wm * 32 + cc) + perm;                // + 64*i + buf*512
    int b_gr = 1024 + 4 * (wn * 32 + cc) + perm;         // + 256*e + 64*j + buf*1280

    // prologue: x[0] regs + DMA B[0] into buf 0
    float4 xreg[2][2];
    xreg[0][0] = *(const float4*)(xrow);
    xreg[0][1] = *(const float4*)(xrow + 4);
    load_lds16(bsrc[0], S + (size_t)bdst_gr[0] * 8);
    load_lds16(bsrc[1], S + (size_t)bdst_gr[1] * 8);
    if (t < 256) load_lds16(bsrc[2], S + (size_t)bdst_gr[2] * 8);

    #pragma unroll
    for (int kc = 0; kc < 12; ++kc) {
        int buf = kc & 1;
        // convert x[kc] -> As[buf]  (loads are one full iteration old)
        float4 a0 = xreg[buf][0], a1 = xreg[buf][1];
        short8 av;
        av[0] = f2bf(a0.x); av[1] = f2bf(a0.y); av[2] = f2bf(a0.z); av[3] = f2bf(a0.w);
        av[4] = f2bf(a1.x); av[5] = f2bf(a1.y); av[6] = f2bf(a1.z); av[7] = f2bf(a1.w);
        *(short8*)&S[(size_t)(buf * 512 + agr) * 8] = av;

        __syncthreads();   // drains DMA B[kc] (a full compute phase old) + As writes

        if (kc < 11) {     // issue next-chunk DMA + x prefetch AFTER the sync
            int nb = 1 - buf;
            int k1 = (kc + 1) * 32;
            load_lds16(bsrc[0] + k1, S + (size_t)(nb * 1280 + bdst_gr[0]) * 8);
            load_lds16(bsrc[1] + k1, S + (size_t)(nb * 1280 + bdst_gr[1]) * 8);
            if (t < 256) load_lds16(bsrc[2] + k1, S + (size_t)(nb * 1280 + bdst_gr[2]) * 8);
            xreg[nb][0] = *(const float4*)(xrow + k1);
            xreg[nb][1] = *(const float4*)(xrow + k1 + 4);
        }

        int ao = buf * 512, bo = buf * 1280;
        short8 af0 = *(const short8*)&S[(size_t)(ao + a_gr) * 8];
        short8 af1 = *(const short8*)&S[(size_t)(ao + a_gr + 64) * 8];
        #pragma unroll
        for (int e = 0; e < NEXP; ++e) {
            short8 b0 = *(const short8*)&S[(size_t)(bo + b_gr + 256 * e) * 8];
            short8 b1 = *(const short8*)&S[(size_t)(bo + b_gr + 256 * e + 64) * 8];
            acc[e][0][0] = __builtin_amdgcn_mfma_f32_16x16x32_bf16(af0, b0, acc[e][0][0], 0, 0, 0);
            acc[e][1][0] = __builtin_amdgcn_mfma_f32_16x16x32_bf16(af1, b0, acc[e][1][0], 0, 0, 0);
            acc[e][0][1] = __builtin_amdgcn_mfma_f32_16x16x32_bf16(af0, b1, acc[e][0][1], 0, 0, 0);
            acc[e][1][1] = __builtin_amdgcn_mfma_f32_16x16x32_bf16(af1, b1, acc[e][1][1], 0, 0, 0);
        }
    }

    // ---- epilogue: gates to LDS (reuse A region), combine + bias + leaky -----------
    __syncthreads();
    float* Gs = (float*)S;
    Gs[t] = G[(size_t)mt * 640 + t];
    if (t < 128) Gs[512 + t] = G[(size_t)mt * 640 + 512 + t];
    float bes[2][NEXP];
    #pragma unroll
    for (int j = 0; j < 2; ++j) {
        int oc = n0 + wn * 32 + j * 16 + cc;
        #pragma unroll
        for (int e = 0; e < NEXP; ++e) bes[j][e] = be[e * CDIM + oc];
    }
    __syncthreads();

    #pragma unroll
    for (int i = 0; i < 2; ++i) {
        #pragma unroll
        for (int r = 0; r < 4; ++r) {
            int trow = wm * 32 + i * 16 + q * 4 + r;     // C/D: col=cc, row=q*4+r
            float g0 = Gs[trow * NEXP + 0], g1 = Gs[trow * NEXP + 1],
                  g2 = Gs[trow * NEXP + 2], g3 = Gs[trow * NEXP + 3],
                  g4 = Gs[trow * NEXP + 4];
            #pragma unroll
            for (int j = 0; j < 2; ++j) {                // j=0,1 halves complete the 128B line
                int oc = n0 + wn * 32 + j * 16 + cc;
                float v = g0 * (acc[0][i][j][r] + bes[j][0]) + g1 * (acc[1][i][j][r] + bes[j][1])
                        + g2 * (acc[2][i][j][r] + bes[j][2]) + g3 * (acc[3][i][j][r] + bes[j][3])
                        + g4 * (acc[4][i][j][r] + bes[j][4]);
                v = v > 0.0f ? v : 0.01f * v;
                out[(size_t)(m0 + trow) * CDIM + oc] = v;
            }
        }
    }
}

extern "C" void kernel_launch(void* const* d_in, const int* in_sizes, int n_in,
                              void* d_out, int out_size, void* d_ws, size_t ws_size,
                              hipStream_t stream) {
    const float* x  = (const float*)d_in[0];
    const float* Wg = (const float*)d_in[1];
    const float* We = (const float*)d_in[2];
    const float* be = (const float*)d_in[3];
    float* out = (float*)d_out;

    float* G = (float*)d_ws;                                                    // 1.31 MB
    unsigned short* WeT =
        (unsigned short*)((char*)d_ws + (size_t)TOKENS * NEXP * sizeof(float)); // 1.47 MB

    router_kernel<<<TOKENS / 256, 256, 0, stream>>>(x, Wg, G);
    convert_we<<<dim3(6, 6, 5), 256, 0, stream>>>(We, WeT);
    moe_kernel<<<(TOKENS / 128) * 6, 512, 0, stream>>>(x, WeT, G, be, out);
}